// Round 4
// baseline (60.736 us; speedup 1.0000x reference)
//
#include <hip/hip_runtime.h>
#include <hip/hip_bf16.h>

typedef __attribute__((ext_vector_type(8))) short short8;
typedef __attribute__((ext_vector_type(4))) float f32x4;
typedef float f4a __attribute__((ext_vector_type(4), aligned(4)));  // align-4 float4

constexpr int NF = 169;
constexpr int NH = 128;
constexpr int R  = 64;    // rows per block

#define MFMA(a, b, c) __builtin_amdgcn_mfma_f32_16x16x32_bf16(a, b, c, 0, 0, 0)

__device__ inline unsigned short f2bf(float f) {
    union { __hip_bfloat16 h; unsigned short u; } c;
    c.h = __float2bfloat16(f);
    return c.u;
}

// Wave-cooperative pooling: wave S computes windows 9S..9S+8 for its lane's row.
// All indices compile-time within each template instantiation (wave-uniform switch).
template<int S>
__device__ inline void pool_case(const float* __restrict__ xr, unsigned short* pool_g, int lane) {
    constexpr int START = (S == 0) ? 0 : (S == 1) ? 28 : (S == 2) ? 84 : 112;
    float gx[72];
    #pragma unroll
    for (int i = 0; i < 18; ++i) {
        const int e = START + 4 * i;
        if (e + 3 < NF) {
            f4a v = *(const f4a*)(xr + e);
            gx[4*i+0] = v[0]; gx[4*i+1] = v[1]; gx[4*i+2] = v[2]; gx[4*i+3] = v[3];
        } else {
            #pragma unroll
            for (int j = 0; j < 4; ++j)
                gx[4*i+j] = (e + j < NF) ? xr[e + j] : 0.0f;
        }
    }
    #pragma unroll
    for (int t = 0; t < 9; ++t) {
        const int w  = S * 9 + t;       // window index = pooled feature k
        const int wi = w / 6, wj = w % 6;
        float s = 0.0f;
        #pragma unroll
        for (int rr = 0; rr < 3; ++rr)
            #pragma unroll
            for (int cc = 0; cc < 3; ++cc) {
                const int gi = (2 * wi + rr) * 14 + (2 * wj + cc);  // compile-time
                if (gi < NF) s += gx[gi - START];                   // pad -> 0
            }
        const float p = fmaxf(s * (1.0f / 9.0f), 0.0f);
        pool_g[((w >> 3) * R + lane) * 8 + (w & 7)] = f2bf(p);
    }
    // zero-fill this wave's share of padded k = 36 + 7S .. 36 + 7S + 6
    #pragma unroll
    for (int z = 0; z < 7; ++z) {
        const int k = 36 + 7 * S + z;
        pool_g[((k >> 3) * R + lane) * 8 + (k & 7)] = 0;
    }
}

// LDS map (29184 B):
//  [0, 16384):      h_g[16][64][8] bf16;  pool_g[8][64][8] aliases [0, 8192)
//  [16384, 28672):  w1g[8][128][8] bf16;  stage[16][169] f32 aliases [16384, 27200)
//  [28672, 29184):  b1s[128] f32
__global__ __launch_bounds__(256, 4) void fused_v4(
    const float* __restrict__ x,
    const float* __restrict__ w1,
    const float* __restrict__ b1,
    const float* __restrict__ w2,
    const float* __restrict__ b2,
    float* __restrict__ out)
{
    __shared__ __align__(16) char smem[29184];
    unsigned short* h_g    = (unsigned short*)smem;            // [16][64][8]
    unsigned short* pool_g = (unsigned short*)smem;            // [8][64][8] (alias)
    unsigned short* w1g    = (unsigned short*)(smem + 16384);  // [8][128][8]
    float*          stage  = (float*)(smem + 16384);           // [16][169] (alias)
    float*          b1s    = (float*)(smem + 28672);           // [128]

    const int tid  = threadIdx.x;
    const int wid  = tid >> 6;
    const int lane = tid & 63;
    const int lr   = lane & 15;
    const int hi   = lane >> 4;

    // ---- stage w1 -> w1g (bf16, k zero-padded 36->64) ----
    #pragma unroll
    for (int it = 0; it < 4; ++it) {
        const int idx = tid + it * 256;   // n*8 + g
        const int n = idx >> 3, g = idx & 7;
        short8 pk;
        #pragma unroll
        for (int j = 0; j < 8; ++j) {
            const int k = g * 8 + j;
            pk[j] = (short)f2bf(k < 36 ? w1[n * 36 + k] : 0.0f);
        }
        *(short8*)(w1g + (g * 128 + n) * 8) = pk;
    }
    if (tid < 128) b1s[tid] = b1[tid];

    // ---- wave-cooperative pooling: row = blk*64 + lane ----
    const long rowBase = (long)blockIdx.x * R;
    const float* __restrict__ xr = x + (rowBase + lane) * NF;
    switch (wid) {
        case 0: pool_case<0>(xr, pool_g, lane); break;
        case 1: pool_case<1>(xr, pool_g, lane); break;
        case 2: pool_case<2>(xr, pool_g, lane); break;
        default: pool_case<3>(xr, pool_g, lane); break;
    }
    __syncthreads();   // (1) pool_g complete

    // ---- A1 fragments (wave owns m-tile = wid) + w2/b2 fragments to regs ----
    short8 afrag[2];
    #pragma unroll
    for (int ks = 0; ks < 2; ++ks)
        afrag[ks] = *(const short8*)(pool_g + ((ks * 4 + hi) * R + wid * 16 + lr) * 8);

    const int nOt = (wid < 3) ? 3 : 2;   // ot = wid + 4t, 11 total
    short8 wfrag[3][4];
    float  bias2[3];
    #pragma unroll
    for (int t = 0; t < 3; ++t) {
        const int ot = wid + 4 * t;
        const int o  = ot * 16 + lr;
        const bool valid = (t < nOt) && (o < NF);
        bias2[t] = valid ? b2[o] : 0.0f;
        #pragma unroll
        for (int ks = 0; ks < 4; ++ks) {
            short8 pk = {0, 0, 0, 0, 0, 0, 0, 0};
            if (valid) {
                const float* wp = w2 + (long)o * NH + ks * 32 + hi * 8;
                f32x4 v0 = *(const f32x4*)(wp);
                f32x4 v1 = *(const f32x4*)(wp + 4);
                #pragma unroll
                for (int j = 0; j < 4; ++j) pk[j]     = (short)f2bf(v0[j]);
                #pragma unroll
                for (int j = 0; j < 4; ++j) pk[4 + j] = (short)f2bf(v1[j]);
            }
            wfrag[t][ks] = pk;
        }
    }
    __syncthreads();   // (2) pool reads done -> h_g region writable

    // ---- GEMM1: h(tile mt=wid) = relu(pooled @ w1^T + b1) -> h_g ----
    short8 b1f[8][2];
    #pragma unroll
    for (int nt = 0; nt < 8; ++nt)
        #pragma unroll
        for (int ks = 0; ks < 2; ++ks)
            b1f[nt][ks] = *(const short8*)(w1g + ((ks * 4 + hi) * 128 + nt * 16 + lr) * 8);
    float bias1[8];
    #pragma unroll
    for (int nt = 0; nt < 8; ++nt) bias1[nt] = b1s[nt * 16 + lr];

    #pragma unroll
    for (int nt = 0; nt < 8; ++nt) {
        f32x4 c = {0.f, 0.f, 0.f, 0.f};
        c = MFMA(afrag[0], b1f[nt][0], c);
        c = MFMA(afrag[1], b1f[nt][1], c);
        const int g = 2 * nt + (lr >> 3);
        const int e = lr & 7;
        #pragma unroll
        for (int r = 0; r < 4; ++r) {
            const float v = fmaxf(c[r] + bias1[nt], 0.0f);
            const int rw = wid * 16 + hi * 4 + r;
            h_g[(g * R + rw) * 8 + e] = f2bf(v);
        }
    }
    __syncthreads();   // (3) h_g complete; w1g dead -> stage usable

    // ---- GEMM2 (ot-split, w2 in regs) + staged coalesced stores ----
    #pragma unroll 1
    for (int mt = 0; mt < 4; ++mt) {
        short8 a2[4];
        #pragma unroll
        for (int ks = 0; ks < 4; ++ks)
            a2[ks] = *(const short8*)(h_g + ((ks * 4 + hi) * R + mt * 16 + lr) * 8);

        f32x4 acc[3];
        #pragma unroll
        for (int t = 0; t < 3; ++t) {
            f32x4 c = {0.f, 0.f, 0.f, 0.f};
            #pragma unroll
            for (int ks = 0; ks < 4; ++ks)
                c = MFMA(a2[ks], wfrag[t][ks], c);
            acc[t] = c;
        }
        #pragma unroll
        for (int t = 0; t < 3; ++t) {
            const int o = (wid + 4 * t) * 16 + lr;
            if (t < nOt && o < NF) {
                #pragma unroll
                for (int r = 0; r < 4; ++r)
                    stage[(hi * 4 + r) * NF + o] = acc[t][r] + bias2[t];
            }
        }
        __syncthreads();   // stage complete for this m-tile

        float* op = out + (rowBase + mt * 16) * NF;
        #pragma unroll
        for (int it = 0; it < 3; ++it) {
            const int i = tid + it * 256;
            if (i < 676) {                      // 16*169/4 float4s
                f32x4 v = *(const f32x4*)(stage + 4 * i);
                *(f32x4*)(op + 4 * i) = v;
            }
        }
        __syncthreads();   // stage consumed before next m-tile
    }
}

extern "C" void kernel_launch(void* const* d_in, const int* in_sizes, int n_in,
                              void* d_out, int out_size, void* d_ws, size_t ws_size,
                              hipStream_t stream) {
    const float* x  = (const float*)d_in[0];
    const float* w1 = (const float*)d_in[1];
    const float* b1 = (const float*)d_in[2];
    const float* w2 = (const float*)d_in[3];
    const float* b2 = (const float*)d_in[4];
    float* out = (float*)d_out;

    const int rows = in_sizes[0] / NF;      // 131072
    const int blocks = rows / R;            // 2048
    fused_v4<<<blocks, 256, 0, stream>>>(x, w1, b1, w2, b2, out);
}